// Round 16
// baseline (184.129 us; speedup 1.0000x reference)
//
#include <hip/hip_runtime.h>
#include <math.h>

#define TOK 32768
#define CH  256
#define HIDN 1024
#define NE  8
#define BE  10240
#define CNT_STRIDE 64

typedef __attribute__((ext_vector_type(8))) short bf16x8;
typedef __attribute__((ext_vector_type(4))) float f32x4;
typedef __attribute__((ext_vector_type(2))) long long2v;

__device__ __forceinline__ unsigned short f2bf(float f) {
    unsigned u = __builtin_bit_cast(unsigned, f);
    unsigned r = 0x7FFFu + ((u >> 16) & 1u);
    return (unsigned short)((u + r) >> 16);
}
__device__ __forceinline__ float bf2f(unsigned short u) {
    return __builtin_bit_cast(float, (unsigned)u << 16);
}
__device__ __forceinline__ unsigned pk8_lo(float a, float b, unsigned old) {
    return (unsigned)__builtin_amdgcn_cvt_pk_fp8_f32(a, b, (int)old, false);
}
__device__ __forceinline__ unsigned pk8_hi(float a, float b, unsigned old) {
    return (unsigned)__builtin_amdgcn_cvt_pk_fp8_f32(a, b, (int)old, true);
}
__device__ __forceinline__ f32x4 mfma8(long a, long b, f32x4 c) {
    return __builtin_amdgcn_mfma_f32_16x16x32_fp8_fp8(a, b, c, 0, 0, 0);
}

typedef __attribute__((address_space(3))) void lds_t;
typedef const __attribute__((address_space(1))) void gm_t;
#define GL16(gp, lp) __builtin_amdgcn_global_load_lds((gm_t*)(gp), (lds_t*)(lp), 16, 0, 0)

// Merged: blocks 0..8191 = depthwise conv (one (n,c) image each, fp8 out);
// blocks 8192..9215 = weight pack (W1 paired A-tiles, W2 natural paired A-tiles).
// Block 0 also zeroes expert counters.
__global__ __launch_bounds__(256) void k_conv(const float* __restrict__ in,
                                              const float* __restrict__ kern,
                                              const float* __restrict__ bias,
                                              const float* __restrict__ w1,
                                              const float* __restrict__ w2,
                                              unsigned char* __restrict__ xc8,
                                              unsigned char* __restrict__ w1p,
                                              unsigned char* __restrict__ w2p,
                                              int* __restrict__ cnt) {
    __shared__ float img[1024];
    __shared__ float kwl[49];
    int t = threadIdx.x;
    int bid = blockIdx.x;

    if (bid >= 8192) {
        int pb = bid - 8192;
        if (pb < 512) {
            // W1 pack: tile (e,hc,h,kp): lane l 16B = [frag ks=2kp | frag ks=2kp+1];
            // frag(ks): row hid = hc*32+h*16+(l&15), k ch = ks*32+(l>>4)*8+b.
            int s = pb * 256 + t;
            int l = s & 63, tile = s >> 6;
            int kp = tile & 3, h = (tile >> 2) & 1, hc = (tile >> 3) & 31, e = tile >> 8;
            int l15 = l & 15, l4 = l >> 4;
            int hid = hc * 32 + h * 16 + l15;
            int ch0 = kp * 64 + l4 * 8;
            const float* s0 = w1 + ((size_t)e * 256 + ch0) * 1024 + hid;
            float v[8], u[8];
#pragma unroll
            for (int b = 0; b < 8; ++b) { v[b] = s0[b * 1024]; u[b] = s0[(b + 32) * 1024]; }
            uint4 o;
            o.x = pk8_hi(v[2], v[3], pk8_lo(v[0], v[1], 0u));
            o.y = pk8_hi(v[6], v[7], pk8_lo(v[4], v[5], 0u));
            o.z = pk8_hi(u[2], u[3], pk8_lo(u[0], u[1], 0u));
            o.w = pk8_hi(u[6], u[7], pk8_lo(u[4], u[5], 0u));
            *(uint4*)(w1p + (size_t)tile * 1024 + l * 16) = o;
        } else {
            // W2 pack (natural k-order, paired by out): tile (e,hc,np): lane l 16B =
            // [frag out=np*32+l15 | frag out=np*32+16+l15]; frag k hid = hc*32+l4*8+b.
            int s = (pb - 512) * 256 + t;
            int l = s & 63, tile = s >> 6;
            int np = tile & 7, hc = (tile >> 3) & 31, e = tile >> 8;
            int l15 = l & 15, l4 = l >> 4;
            int hid0 = hc * 32 + l4 * 8;
            int col0 = np * 32 + l15;
            const float* s0 = w2 + ((size_t)e * 1024 + hid0) * 256 + col0;
            float v[8], u[8];
#pragma unroll
            for (int b = 0; b < 8; ++b) { v[b] = s0[b * 256]; u[b] = s0[b * 256 + 16]; }
            uint4 o;
            o.x = pk8_hi(v[2], v[3], pk8_lo(v[0], v[1], 0u));
            o.y = pk8_hi(v[6], v[7], pk8_lo(v[4], v[5], 0u));
            o.z = pk8_hi(u[2], u[3], pk8_lo(u[0], u[1], 0u));
            o.w = pk8_hi(u[6], u[7], pk8_lo(u[4], u[5], 0u));
            *(uint4*)(w2p + (size_t)tile * 1024 + l * 16) = o;
        }
        return;
    }

    int c = bid & 255;
    if (bid == 0) { cnt[t] = 0; cnt[t + 256] = 0; }

    GL16(in + (size_t)bid * 1024 + t * 4, (char*)img + t * 16);
    if (t < 49) kwl[t] = kern[c * 49 + t];
    __syncthreads();

    int x0 = (t & 7) * 4, y = t >> 3;
    float b0 = bias[c];
    float acc[4] = {b0, b0, b0, b0};
#pragma unroll
    for (int jr = 0; jr < 7; ++jr) {
        int yy = y + jr - 3;
        if ((unsigned)yy < 32u) {
            float row[10];
#pragma unroll
            for (int k = 0; k < 10; ++k) {
                int xx = x0 - 3 + k;
                row[k] = ((unsigned)xx < 32u) ? img[yy * 32 + xx] : 0.f;
            }
#pragma unroll
            for (int kx = 0; kx < 7; ++kx) {
                float kv = kwl[jr * 7 + kx];
#pragma unroll
                for (int o = 0; o < 4; ++o) acc[o] = fmaf(row[o + kx], kv, acc[o]);
            }
        }
    }
    unsigned u = pk8_lo(acc[0], acc[1], 0u);
    u = pk8_hi(acc[2], acc[3], u);
    *(unsigned*)(xc8 + (size_t)bid * 1024 + y * 32 + x0) = u;
}

// LN + router: block = (n,y) row. Coalesced fp8 4B loads, decode, LDS
// transpose, then per-wave LN + top-2 router.
__global__ __launch_bounds__(512) void k_lnr(const unsigned char* __restrict__ xc8,
                                             const float* __restrict__ gamma,
                                             const float* __restrict__ beta,
                                             const float* __restrict__ rw,
                                             unsigned* __restrict__ xf8,
                                             int* __restrict__ e01,
                                             float2* __restrict__ gates) {
    __shared__ float acc[32][260];
    int t = threadIdx.x;
    int n = blockIdx.x >> 5, y = blockIdx.x & 31;
    int x4 = t & 7, ch = t >> 3;   // ch in [0,64)

#pragma unroll
    for (int i = 0; i < 4; ++i) {
        int c = i * 64 + ch;
        unsigned word = *(const unsigned*)(xc8 + ((size_t)(n * 256 + c)) * 1024 + y * 32 + x4 * 4);
        acc[x4 * 4 + 0][c] = __builtin_amdgcn_cvt_f32_fp8((int)word, 0);
        acc[x4 * 4 + 1][c] = __builtin_amdgcn_cvt_f32_fp8((int)word, 1);
        acc[x4 * 4 + 2][c] = __builtin_amdgcn_cvt_f32_fp8((int)word, 2);
        acc[x4 * 4 + 3][c] = __builtin_amdgcn_cvt_f32_fp8((int)word, 3);
    }
    __syncthreads();

    int lane = t & 63, w = t >> 6;
    float4 g4 = ((const float4*)gamma)[lane];
    float4 b4 = ((const float4*)beta)[lane];
    int c0 = lane * 4;
    float4 rwv[8];
#pragma unroll
    for (int j = 0; j < 4; ++j) {
        rwv[j * 2]     = *(const float4*)(rw + (size_t)(c0 + j) * 8);
        rwv[j * 2 + 1] = *(const float4*)(rw + (size_t)(c0 + j) * 8 + 4);
    }

#pragma unroll
    for (int k = 0; k < 4; ++k) {
        int tl = w * 4 + k;
        float4 v = *(const float4*)&acc[tl][lane * 4];
        float s = v.x + v.y + v.z + v.w;
        float q = v.x * v.x + v.y * v.y + v.z * v.z + v.w * v.w;
#pragma unroll
        for (int m = 1; m < 64; m <<= 1) { s += __shfl_xor(s, m); q += __shfl_xor(q, m); }
        float mean = s * (1.0f / 256.0f);
        float var  = q * (1.0f / 256.0f) - mean * mean;
        float rstd = rsqrtf(var + 1e-6f);

        float xn[4];
        xn[0] = (v.x - mean) * rstd * g4.x + b4.x;
        xn[1] = (v.y - mean) * rstd * g4.y + b4.y;
        xn[2] = (v.z - mean) * rstd * g4.z + b4.z;
        xn[3] = (v.w - mean) * rstd * g4.w + b4.w;

        unsigned px = pk8_lo(xn[0], xn[1], 0u);
        px = pk8_hi(xn[2], xn[3], px);
        int tok = n * 1024 + y * 32 + tl;
        xf8[tok * 64 + lane] = px;

        float p[8];
#pragma unroll
        for (int e = 0; e < 8; ++e) p[e] = 0.f;
#pragma unroll
        for (int j = 0; j < 4; ++j) {
            float xv = xn[j];
            const float* r0 = (const float*)&rwv[j * 2];
#pragma unroll
            for (int e = 0; e < 8; ++e) p[e] += xv * r0[e];
        }
#pragma unroll
        for (int m = 1; m < 64; m <<= 1) {
#pragma unroll
            for (int e = 0; e < 8; ++e) p[e] += __shfl_xor(p[e], m);
        }
        if (lane == 0) {
            int e0 = 0; float l0 = p[0];
#pragma unroll
            for (int e = 1; e < 8; ++e) if (p[e] > l0) { l0 = p[e]; e0 = e; }
            int e1 = -1; float l1 = -3.4e38f;
#pragma unroll
            for (int e = 0; e < 8; ++e) if (e != e0 && p[e] > l1) { l1 = p[e]; e1 = e; }
            float tt = expf(l1 - l0);
            float w0 = 1.0f / (1.0f + tt);
            e01[tok] = e0 | (e1 << 8);
            gates[tok] = make_float2(w0, 1.0f - w0);
        }
    }
}

// Hierarchical capacity assignment.
__global__ __launch_bounds__(256) void k_assign(const int* __restrict__ e01,
                                                int* __restrict__ cnt,
                                                int* __restrict__ row_token,
                                                int2* __restrict__ slots) {
    __shared__ int lcnt[8];
    __shared__ int base[8];
    int t = threadIdx.x;
    if (t < 8) lcnt[t] = 0;
    __syncthreads();
    int tok = blockIdx.x * 256 + t;
    int ee = e01[tok];
    int e0 = ee & 255, e1 = (ee >> 8) & 255;
    int lp0 = atomicAdd(&lcnt[e0], 1);
    int lp1 = atomicAdd(&lcnt[e1], 1);
    __syncthreads();
    if (t < 8) base[t] = atomicAdd(cnt + t * CNT_STRIDE, lcnt[t]);
    __syncthreads();
    int pos0 = base[e0] + lp0;
    int pos1 = base[e1] + lp1;
    int slot0 = (pos0 < BE) ? e0 * BE + pos0 : -1;
    int slot1 = (pos1 < BE) ? e1 * BE + pos1 : -1;
    if (slot0 >= 0) row_token[slot0] = tok;
    if (slot1 >= 0) row_token[slot1] = tok;
    slots[tok] = make_int2(slot0, slot1);
}

// Fused expert MLP v8: paired-wave split. 256 threads = 2 pairs x 2 waves,
// 64 rows/block, e = bid&7. Pair p owns 32 tokens; within a pair, wave s
// computes hid-half s (A-part) and out-half s (B-part) -> each wave reads
// only HALF of W1 and W2 per step (8 b128 vs 16). H crosses the pair via a
// small double-buffered LDS tile (36B pitch, conflict-free), visible at the
// existing per-step barrier (lgkmcnt(0) added). W1 2-buf + W2 3-buf,
// 4 GL16/step, counted vmcnt(2), 1 barrier/step.
__global__ __launch_bounds__(256, 3) void k_mlp(const unsigned char* __restrict__ xf8,
                                                const unsigned char* __restrict__ w1p,
                                                const unsigned char* __restrict__ w2p,
                                                const float* __restrict__ b1,
                                                const float* __restrict__ b2,
                                                const int* __restrict__ cnt,
                                                const int* __restrict__ row_token,
                                                unsigned short* __restrict__ Y) {
    int bid = blockIdx.x;
    int e = bid & 7;
    int row0 = (bid >> 3) * 64;
    int nrows = min(cnt[e * CNT_STRIDE], BE);
    if (row0 >= nrows) return;

    __shared__ char smem[49664];
    char* const W1S0 = smem;
    char* const W1S1 = smem + 8192;
    char* const W2S0 = smem + 16384;
    char* const W2S1 = smem + 24576;
    char* const W2S2 = smem + 32768;
    char* const b1lds = smem + 40960;     // 4KB
    char* const Hbase = smem + 45056;     // 2 bufs x (2 pairs x 1152B) = 4608B

    int t = threadIdx.x;
    int w = t >> 6, lane = t & 63;
    int l15 = lane & 15, l4 = lane >> 4;
    int p = w >> 1, s = w & 1;            // pair, sub-role

    const unsigned char* w1e = w1p + (size_t)e * 262144;
    const unsigned char* w2e = w2p + (size_t)e * 262144;

    // X -> VGPR: pair's 32 tokens (2 tok-frags), duplicated across the pair.
    int ri = row0 + p * 32 + l15;
    int tokA = (ri < nrows) ? row_token[e * BE + ri] : 0;
    int tokB = (ri + 16 < nrows) ? row_token[e * BE + ri + 16] : 0;
    long xr[2][8];
#pragma unroll
    for (int ks = 0; ks < 8; ++ks) {
        xr[0][ks] = *(const long*)(xf8 + (size_t)tokA * 256 + ks * 32 + l4 * 8);
        xr[1][ks] = *(const long*)(xf8 + (size_t)tokB * 256 + ks * 32 + l4 * 8);
    }

    // prologue: b1, W1(0), W2(0)
    GL16((const char*)(b1 + e * HIDN) + t * 16, b1lds + t * 16);
    GL16(w1e + t * 16, W1S0 + t * 16);
    GL16(w1e + 4096 + t * 16, W1S0 + 4096 + t * 16);
    GL16(w2e + t * 16, W2S0 + t * 16);
    GL16(w2e + 4096 + t * 16, W2S0 + 4096 + t * 16);
    __builtin_amdgcn_sched_barrier(0);
    asm volatile("s_waitcnt vmcnt(2)" ::: "memory");
    __builtin_amdgcn_s_barrier();
    __builtin_amdgcn_sched_barrier(0);

    f32x4 yacc[16];
#pragma unroll
    for (int nc = 0; nc < 16; ++nc) yacc[nc] = f32x4{0.f, 0.f, 0.f, 0.f};

    auto STEP = [&](const char* w1c, const char* w2r, char* w1f_, char* w2f_,
                    const unsigned char* g1, const unsigned char* g2,
                    bool doStage, bool doB, const char* hR, char* hW,
                    int b1off, bool last) {
        if (doStage) {
            GL16(g1 + t * 16, w1f_ + t * 16);
            GL16(g1 + 4096 + t * 16, w1f_ + 4096 + t * 16);
            GL16(g2 + t * 16, w2f_ + t * 16);
            GL16(g2 + 4096 + t * 16, w2f_ + 4096 + t * 16);
        }
        // A: ha[tf] = W1(hid-half s) @ X(tf). D: col=tok l15, row=hid l4*4+j.
        long w1fr[8];
#pragma unroll
        for (int kp = 0; kp < 4; ++kp) {
            long2v q = *(const long2v*)(w1c + (s * 4 + kp) * 1024 + lane * 16);
            w1fr[kp * 2] = q.x;
            w1fr[kp * 2 + 1] = q.y;
        }
        f32x4 ha0 = f32x4{0.f, 0.f, 0.f, 0.f};
        f32x4 ha1 = f32x4{0.f, 0.f, 0.f, 0.f};
#pragma unroll
        for (int ks = 0; ks < 8; ++ks) {
            ha0 = mfma8(w1fr[ks], xr[0][ks], ha0);
            ha1 = mfma8(w1fr[ks], xr[1][ks], ha1);
        }
        // B: yacc += W2(out-half s, prev) @ H(prev) -- H from pair LDS tile.
        if (doB) {
            long hb0 = *(const long*)(hR + p * 1152 + l15 * 36 + l4 * 8);
            long hb1 = *(const long*)(hR + p * 1152 + (16 + l15) * 36 + l4 * 8);
#pragma unroll
            for (int jp = 0; jp < 4; ++jp) {
                long2v q = *(const long2v*)(w2r + (s * 4 + jp) * 1024 + lane * 16);
                yacc[jp * 4 + 0] = mfma8(q.x, hb0, yacc[jp * 4 + 0]);
                yacc[jp * 4 + 1] = mfma8(q.x, hb1, yacc[jp * 4 + 1]);
                yacc[jp * 4 + 2] = mfma8(q.y, hb0, yacc[jp * 4 + 2]);
                yacc[jp * 4 + 3] = mfma8(q.y, hb1, yacc[jp * 4 + 3]);
            }
        }
        // gelu (sigmoid form) + pack -> pair H tile (natural hid order)
        float4 bv = *(const float4*)(b1lds + b1off + s * 64 + l4 * 16);
        float g[4];
#pragma unroll
        for (int j = 0; j < 4; ++j) {
            float vv = ha0[j] + ((const float*)&bv)[j];
            g[j] = vv * __builtin_amdgcn_rcpf(1.0f + __builtin_amdgcn_exp2f(-2.4554672f * vv));
        }
        unsigned pk0 = pk8_hi(g[2], g[3], pk8_lo(g[0], g[1], 0u));
#pragma unroll
        for (int j = 0; j < 4; ++j) {
            float vv = ha1[j] + ((const float*)&bv)[j];
            g[j] = vv * __builtin_amdgcn_rcpf(1.0f + __builtin_amdgcn_exp2f(-2.4554672f * vv));
        }
        unsigned pk1 = pk8_hi(g[2], g[3], pk8_lo(g[0], g[1], 0u));
        *(unsigned*)(hW + p * 1152 + l15 * 36 + s * 16 + l4 * 4) = pk0;
        *(unsigned*)(hW + p * 1152 + (16 + l15) * 36 + s * 16 + l4 * 4) = pk1;

        __builtin_amdgcn_sched_barrier(0);
        if (last) asm volatile("s_waitcnt vmcnt(0) lgkmcnt(0)" ::: "memory");
        else      asm volatile("s_waitcnt vmcnt(2) lgkmcnt(0)" ::: "memory");
        __builtin_amdgcn_s_barrier();
        __builtin_amdgcn_sched_barrier(0);
    };

    char* const H0 = Hbase;
    char* const H1 = Hbase + 2304;

    const char *w1r = W1S0, *w1f = W1S1;
    const char *w2red = W2S2, *w2cur = W2S0, *w2fil = W2S1;
    const unsigned char* g1 = w1e + 8192;
    const unsigned char* g2 = w2e + 8192;
    int b1off = 0;

#define ROTATE() { const char* _a = w1r; w1r = w1f; w1f = _a; \
                   const char* _b = w2red; w2red = w2cur; w2cur = w2fil; w2fil = _b; \
                   g1 += 8192; g2 += 8192; b1off += 128; }

    // step 0: A only, write H0
    STEP(w1r, w2red, (char*)w1f, (char*)w2fil, g1, g2, true, false, H1, H0, b1off, false);
    ROTATE();
    for (int i = 0; i < 5; ++i) {
        STEP(w1r, w2red, (char*)w1f, (char*)w2fil, g1, g2, true, true, H0, H1, b1off, false); ROTATE();
        STEP(w1r, w2red, (char*)w1f, (char*)w2fil, g1, g2, true, true, H1, H0, b1off, false); ROTATE();
        STEP(w1r, w2red, (char*)w1f, (char*)w2fil, g1, g2, true, true, H0, H1, b1off, false); ROTATE();
        STEP(w1r, w2red, (char*)w1f, (char*)w2fil, g1, g2, true, true, H1, H0, b1off, false); ROTATE();
        STEP(w1r, w2red, (char*)w1f, (char*)w2fil, g1, g2, true, true, H0, H1, b1off, false); ROTATE();
        STEP(w1r, w2red, (char*)w1f, (char*)w2fil, g1, g2, true, true, H1, H0, b1off, false); ROTATE();
    }
    // step 31: no stage, read H0, write H1
    STEP(w1r, w2red, (char*)w1f, (char*)w2fil, g1, g2, false, true, H0, H1, b1off, true);
    // final B: H(31) from H1 @ W2(31) (= w2cur)
    {
        long hb0 = *(const long*)(H1 + p * 1152 + l15 * 36 + l4 * 8);
        long hb1 = *(const long*)(H1 + p * 1152 + (16 + l15) * 36 + l4 * 8);
        asm volatile("s_waitcnt lgkmcnt(0)" ::: "memory");
        __builtin_amdgcn_sched_barrier(0);
#pragma unroll
        for (int jp = 0; jp < 4; ++jp) {
            long2v q = *(const long2v*)(w2cur + (s * 4 + jp) * 1024 + lane * 16);
            yacc[jp * 4 + 0] = mfma8(q.x, hb0, yacc[jp * 4 + 0]);
            yacc[jp * 4 + 1] = mfma8(q.x, hb1, yacc[jp * 4 + 1]);
            yacc[jp * 4 + 2] = mfma8(q.y, hb0, yacc[jp * 4 + 2]);
            yacc[jp * 4 + 3] = mfma8(q.y, hb1, yacc[jp * 4 + 3]);
        }
    }
#undef ROTATE

    // epilogue: +b2, pack bf16, 520B-pitch LDS transpose, coalesced copy out.
    // yacc[jp*4 + half*2 + tf]: tok = p*32 + tf*16 + l15,
    // out = s*128 + jp*32 + half*16 + l4*4 + j.
    __syncthreads();
#pragma unroll
    for (int jp = 0; jp < 4; ++jp) {
#pragma unroll
        for (int half = 0; half < 2; ++half) {
            int outb = s * 128 + jp * 32 + half * 16 + l4 * 4;
            float4 bv = *(const float4*)(b2 + e * 256 + outb);
#pragma unroll
            for (int tf = 0; tf < 2; ++tf) {
                f32x4 av = yacc[jp * 4 + half * 2 + tf];
                int lrow = p * 32 + tf * 16 + l15;
#pragma unroll
                for (int jq = 0; jq < 2; ++jq) {
                    float a0 = av[jq * 2] + ((const float*)&bv)[jq * 2];
                    float a1 = av[jq * 2 + 1] + ((const float*)&bv)[jq * 2 + 1];
                    unsigned pkv = (unsigned)f2bf(a0) | ((unsigned)f2bf(a1) << 16);
                    *(unsigned*)(smem + lrow * 520 + (outb + jq * 2) * 2) = pkv;
                }
            }
        }
    }
    __syncthreads();
    {
        char* Yg = (char*)(Y + ((size_t)e * BE + row0) * 256);
#pragma unroll
        for (int i = 0; i < 8; ++i) {
            int flat = i * 4096 + t * 16;
            int row = flat >> 9, off = flat & 511;
            *(int4*)(Yg + row * 512 + off) = *(const int4*)(smem + row * 520 + off);
        }
    }
}

// Gather expert outputs (bf16), gate, add residual, write NCHW.
__global__ __launch_bounds__(256) void k_gather(const float* __restrict__ input,
                                                const unsigned short* __restrict__ Y,
                                                const int2* __restrict__ slots,
                                                const float2* __restrict__ gates,
                                                const float* __restrict__ ls,
                                                float* __restrict__ out) {
    __shared__ float acc[32][257];
    int t = threadIdx.x;
    int n = blockIdx.x >> 5, y = blockIdx.x & 31;

    {
        int tl = t & 31, chunk = t >> 5;
        int tok = n * 1024 + y * 32 + tl;
        int2  sl = slots[tok];
        float2 gw = gates[tok];
        int c0 = chunk * 32;
#pragma unroll
        for (int i = 0; i < 4; ++i) {
            int c = c0 + i * 8;
            float v[8];
#pragma unroll
            for (int k = 0; k < 8; ++k) v[k] = 0.f;
            if (sl.x >= 0) {
                bf16x8 yv = *(const bf16x8*)(Y + (size_t)sl.x * 256 + c);
#pragma unroll
                for (int k = 0; k < 8; ++k) v[k] += gw.x * bf2f((unsigned short)yv[k]);
            }
            if (sl.y >= 0) {
                bf16x8 yv = *(const bf16x8*)(Y + (size_t)sl.y * 256 + c);
#pragma unroll
                for (int k = 0; k < 8; ++k) v[k] += gw.y * bf2f((unsigned short)yv[k]);
            }
#pragma unroll
            for (int k = 0; k < 8; ++k) acc[tl][c + k] = v[k];
        }
    }
    __syncthreads();
    {
        int x = t & 31, c8 = t >> 5;
        size_t base = (size_t)n * 256 * 1024 + (size_t)y * 32 + x;
#pragma unroll
        for (int p = 0; p < 32; ++p) {
            int c = p * 8 + c8;
            size_t id = base + (size_t)c * 1024;
            out[id] = input[id] + ls[c] * acc[x][c];
        }
    }
}

extern "C" void kernel_launch(void* const* d_in, const int* in_sizes, int n_in,
                              void* d_out, int out_size, void* d_ws, size_t ws_size,
                              hipStream_t stream) {
    const float* input = (const float*)d_in[0];
    const float* dwk   = (const float*)d_in[1];
    const float* dwb   = (const float*)d_in[2];
    const float* gamma = (const float*)d_in[3];
    const float* beta  = (const float*)d_in[4];
    const float* rw    = (const float*)d_in[5];
    const float* w1    = (const float*)d_in[6];
    const float* b1    = (const float*)d_in[7];
    const float* w2    = (const float*)d_in[8];
    const float* b2    = (const float*)d_in[9];
    const float* ls    = (const float*)d_in[10];

    char* ws = (char*)d_ws;
    // xc8 (16.8MB fp8 conv out) aliases Yb (40MB): xc8 dead before k_mlp writes Yb.
    unsigned char*  xc8  = (unsigned char*)ws;
    unsigned short* Yb   = (unsigned short*)ws;
    unsigned*       xf8  = (unsigned*)(ws + 83886080);         // 8MB fp8 x
    unsigned char*  w1p  = (unsigned char*)(ws + 100663296);   // 2MB paired tiles
    unsigned char*  w2p  = (unsigned char*)(ws + 104857600);   // 2MB paired tiles
    int*            rtok = (int*)(ws + 109051904);             // 320KB
    int2*           slots = (int2*)(ws + 109379584);           // 256KB
    float2*         gates = (float2*)(ws + 109641728);         // 256KB
    int*            e01  = (int*)(ws + 109903872);             // 128KB
    int*            cnt  = (int*)(ws + 110035968);             // 8*64 ints

    k_conv<<<9216, 256, 0, stream>>>(input, dwk, dwb, w1, w2, xc8, w1p, w2p, cnt);
    k_lnr<<<1024, 512, 0, stream>>>(xc8, gamma, beta, rw, xf8, e01, gates);
    k_assign<<<128, 256, 0, stream>>>(e01, cnt, rtok, slots);
    k_mlp<<<1280, 256, 0, stream>>>((const unsigned char*)xf8, w1p, w2p, b1, b2, cnt, rtok, Yb);
    k_gather<<<1024, 256, 0, stream>>>(input, Yb, slots, gates, ls, (float*)d_out);
}

// Round 18
// 153.770 us; speedup vs baseline: 1.1974x; 1.1974x over previous
//
#include <hip/hip_runtime.h>
#include <math.h>

#define TOK 32768
#define CH  256
#define HIDN 1024
#define NE  8
#define BE  10240
#define CNT_STRIDE 64

typedef __attribute__((ext_vector_type(8))) short bf16x8;
typedef __attribute__((ext_vector_type(4))) float f32x4;
typedef __attribute__((ext_vector_type(2))) long long2v;

__device__ __forceinline__ unsigned short f2bf(float f) {
    unsigned u = __builtin_bit_cast(unsigned, f);
    unsigned r = 0x7FFFu + ((u >> 16) & 1u);
    return (unsigned short)((u + r) >> 16);
}
__device__ __forceinline__ float bf2f(unsigned short u) {
    return __builtin_bit_cast(float, (unsigned)u << 16);
}
__device__ __forceinline__ unsigned pk8_lo(float a, float b, unsigned old) {
    return (unsigned)__builtin_amdgcn_cvt_pk_fp8_f32(a, b, (int)old, false);
}
__device__ __forceinline__ unsigned pk8_hi(float a, float b, unsigned old) {
    return (unsigned)__builtin_amdgcn_cvt_pk_fp8_f32(a, b, (int)old, true);
}
__device__ __forceinline__ f32x4 mfma8(long a, long b, f32x4 c) {
    return __builtin_amdgcn_mfma_f32_16x16x32_fp8_fp8(a, b, c, 0, 0, 0);
}
__device__ __forceinline__ void dec8x4(unsigned wvv, float* o) {
    o[0] = __builtin_amdgcn_cvt_f32_fp8((int)wvv, 0);
    o[1] = __builtin_amdgcn_cvt_f32_fp8((int)wvv, 1);
    o[2] = __builtin_amdgcn_cvt_f32_fp8((int)wvv, 2);
    o[3] = __builtin_amdgcn_cvt_f32_fp8((int)wvv, 3);
}

typedef __attribute__((address_space(3))) void lds_t;
typedef const __attribute__((address_space(1))) void gm_t;
#define GL16(gp, lp) __builtin_amdgcn_global_load_lds((gm_t*)(gp), (lds_t*)(lp), 16, 0, 0)

// Merged: blocks 0..8191 = depthwise conv (one (n,c) image each, fp8 out);
// blocks 8192..9215 = weight pack (W1 paired A-tiles, W2 permuted paired tiles).
// Block 0 also zeroes expert counters.
__global__ __launch_bounds__(256) void k_conv(const float* __restrict__ in,
                                              const float* __restrict__ kern,
                                              const float* __restrict__ bias,
                                              const float* __restrict__ w1,
                                              const float* __restrict__ w2,
                                              unsigned char* __restrict__ xc8,
                                              unsigned char* __restrict__ w1p,
                                              unsigned char* __restrict__ w2p,
                                              int* __restrict__ cnt) {
    __shared__ float img[1024];
    __shared__ float kwl[49];
    int t = threadIdx.x;
    int bid = blockIdx.x;

    if (bid >= 8192) {
        int pb = bid - 8192;
        if (pb < 512) {
            // W1 pack: tile (e,hc,h,kp): lane l 16B = [frag ks=2kp | frag ks=2kp+1];
            // frag(ks): row hid = hc*32+h*16+(l&15), k ch = ks*32+(l>>4)*8+b.
            int s = pb * 256 + t;
            int l = s & 63, tile = s >> 6;
            int kp = tile & 3, h = (tile >> 2) & 1, hc = (tile >> 3) & 31, e = tile >> 8;
            int l15 = l & 15, l4 = l >> 4;
            int hid = hc * 32 + h * 16 + l15;
            int ch0 = kp * 64 + l4 * 8;
            const float* s0 = w1 + ((size_t)e * 256 + ch0) * 1024 + hid;
            float v[8], u[8];
#pragma unroll
            for (int b = 0; b < 8; ++b) { v[b] = s0[b * 1024]; u[b] = s0[(b + 32) * 1024]; }
            uint4 o;
            o.x = pk8_hi(v[2], v[3], pk8_lo(v[0], v[1], 0u));
            o.y = pk8_hi(v[6], v[7], pk8_lo(v[4], v[5], 0u));
            o.z = pk8_hi(u[2], u[3], pk8_lo(u[0], u[1], 0u));
            o.w = pk8_hi(u[6], u[7], pk8_lo(u[4], u[5], 0u));
            *(uint4*)(w1p + (size_t)tile * 1024 + l * 16) = o;
        } else {
            // W2 pack (H-permuted k-order): k-position p holds
            // hid 16*((p>>2)&1)+4*(p>>3)+(p&3) -> zero-shuffle H->B.
            int s = (pb - 512) * 256 + t;
            int l = s & 63, tile = s >> 6;
            int np = tile & 7, hc = (tile >> 3) & 31, e = tile >> 8;
            int l15 = l & 15, l4 = l >> 4;
            float v[8], u[8];
#pragma unroll
            for (int b = 0; b < 8; ++b) {
                int hidl = ((b >> 2) & 1) * 16 + l4 * 4 + (b & 3);
                const float* s0 = w2 + ((size_t)e * 1024 + hc * 32 + hidl) * 256 + np * 32 + l15;
                v[b] = s0[0];
                u[b] = s0[16];
            }
            uint4 o;
            o.x = pk8_hi(v[2], v[3], pk8_lo(v[0], v[1], 0u));
            o.y = pk8_hi(v[6], v[7], pk8_lo(v[4], v[5], 0u));
            o.z = pk8_hi(u[2], u[3], pk8_lo(u[0], u[1], 0u));
            o.w = pk8_hi(u[6], u[7], pk8_lo(u[4], u[5], 0u));
            *(uint4*)(w2p + (size_t)tile * 1024 + l * 16) = o;
        }
        return;
    }

    int c = bid & 255;
    if (bid == 0) { cnt[t] = 0; cnt[t + 256] = 0; }

    GL16(in + (size_t)bid * 1024 + t * 4, (char*)img + t * 16);
    if (t < 49) kwl[t] = kern[c * 49 + t];
    __syncthreads();

    int x0 = (t & 7) * 4, y = t >> 3;
    float b0 = bias[c];
    float acc[4] = {b0, b0, b0, b0};
#pragma unroll
    for (int jr = 0; jr < 7; ++jr) {
        int yy = y + jr - 3;
        if ((unsigned)yy < 32u) {
            float row[10];
#pragma unroll
            for (int k = 0; k < 10; ++k) {
                int xx = x0 - 3 + k;
                row[k] = ((unsigned)xx < 32u) ? img[yy * 32 + xx] : 0.f;
            }
#pragma unroll
            for (int kx = 0; kx < 7; ++kx) {
                float kv = kwl[jr * 7 + kx];
#pragma unroll
                for (int o = 0; o < 4; ++o) acc[o] = fmaf(row[o + kx], kv, acc[o]);
            }
        }
    }
    unsigned u = pk8_lo(acc[0], acc[1], 0u);
    u = pk8_hi(acc[2], acc[3], u);
    *(unsigned*)(xc8 + (size_t)bid * 1024 + y * 32 + x0) = u;
}

// LN + router: block = (n,y) row. Coalesced fp8 4B loads, decode, LDS
// transpose, then per-wave LN + top-2 router.
__global__ __launch_bounds__(512) void k_lnr(const unsigned char* __restrict__ xc8,
                                             const float* __restrict__ gamma,
                                             const float* __restrict__ beta,
                                             const float* __restrict__ rw,
                                             unsigned* __restrict__ xf8,
                                             int* __restrict__ e01,
                                             float2* __restrict__ gates) {
    __shared__ float acc[32][260];
    int t = threadIdx.x;
    int n = blockIdx.x >> 5, y = blockIdx.x & 31;
    int x4 = t & 7, ch = t >> 3;   // ch in [0,64)

#pragma unroll
    for (int i = 0; i < 4; ++i) {
        int c = i * 64 + ch;
        unsigned word = *(const unsigned*)(xc8 + ((size_t)(n * 256 + c)) * 1024 + y * 32 + x4 * 4);
        float d[4];
        dec8x4(word, d);
        acc[x4 * 4 + 0][c] = d[0];
        acc[x4 * 4 + 1][c] = d[1];
        acc[x4 * 4 + 2][c] = d[2];
        acc[x4 * 4 + 3][c] = d[3];
    }
    __syncthreads();

    int lane = t & 63, w = t >> 6;
    float4 g4 = ((const float4*)gamma)[lane];
    float4 b4 = ((const float4*)beta)[lane];
    int c0 = lane * 4;
    float4 rwv[8];
#pragma unroll
    for (int j = 0; j < 4; ++j) {
        rwv[j * 2]     = *(const float4*)(rw + (size_t)(c0 + j) * 8);
        rwv[j * 2 + 1] = *(const float4*)(rw + (size_t)(c0 + j) * 8 + 4);
    }

#pragma unroll
    for (int k = 0; k < 4; ++k) {
        int tl = w * 4 + k;
        float4 v = *(const float4*)&acc[tl][lane * 4];
        float s = v.x + v.y + v.z + v.w;
        float q = v.x * v.x + v.y * v.y + v.z * v.z + v.w * v.w;
#pragma unroll
        for (int m = 1; m < 64; m <<= 1) { s += __shfl_xor(s, m); q += __shfl_xor(q, m); }
        float mean = s * (1.0f / 256.0f);
        float var  = q * (1.0f / 256.0f) - mean * mean;
        float rstd = rsqrtf(var + 1e-6f);

        float xn[4];
        xn[0] = (v.x - mean) * rstd * g4.x + b4.x;
        xn[1] = (v.y - mean) * rstd * g4.y + b4.y;
        xn[2] = (v.z - mean) * rstd * g4.z + b4.z;
        xn[3] = (v.w - mean) * rstd * g4.w + b4.w;

        unsigned px = pk8_lo(xn[0], xn[1], 0u);
        px = pk8_hi(xn[2], xn[3], px);
        int tok = n * 1024 + y * 32 + tl;
        xf8[tok * 64 + lane] = px;

        float p[8];
#pragma unroll
        for (int e = 0; e < 8; ++e) p[e] = 0.f;
#pragma unroll
        for (int j = 0; j < 4; ++j) {
            float xv = xn[j];
            const float* r0 = (const float*)&rwv[j * 2];
#pragma unroll
            for (int e = 0; e < 8; ++e) p[e] += xv * r0[e];
        }
#pragma unroll
        for (int m = 1; m < 64; m <<= 1) {
#pragma unroll
            for (int e = 0; e < 8; ++e) p[e] += __shfl_xor(p[e], m);
        }
        if (lane == 0) {
            int e0 = 0; float l0 = p[0];
#pragma unroll
            for (int e = 1; e < 8; ++e) if (p[e] > l0) { l0 = p[e]; e0 = e; }
            int e1 = -1; float l1 = -3.4e38f;
#pragma unroll
            for (int e = 0; e < 8; ++e) if (e != e0 && p[e] > l1) { l1 = p[e]; e1 = e; }
            float tt = expf(l1 - l0);
            float w0 = 1.0f / (1.0f + tt);
            e01[tok] = e0 | (e1 << 8);
            gates[tok] = make_float2(w0, 1.0f - w0);
        }
    }
}

// Hierarchical capacity assignment.
__global__ __launch_bounds__(256) void k_assign(const int* __restrict__ e01,
                                                int* __restrict__ cnt,
                                                int* __restrict__ row_token,
                                                int2* __restrict__ slots) {
    __shared__ int lcnt[8];
    __shared__ int base[8];
    int t = threadIdx.x;
    if (t < 8) lcnt[t] = 0;
    __syncthreads();
    int tok = blockIdx.x * 256 + t;
    int ee = e01[tok];
    int e0 = ee & 255, e1 = (ee >> 8) & 255;
    int lp0 = atomicAdd(&lcnt[e0], 1);
    int lp1 = atomicAdd(&lcnt[e1], 1);
    __syncthreads();
    if (t < 8) base[t] = atomicAdd(cnt + t * CNT_STRIDE, lcnt[t]);
    __syncthreads();
    int pos0 = base[e0] + lp0;
    int pos1 = base[e1] + lp1;
    int slot0 = (pos0 < BE) ? e0 * BE + pos0 : -1;
    int slot1 = (pos1 < BE) ? e1 * BE + pos1 : -1;
    if (slot0 >= 0) row_token[slot0] = tok;
    if (slot1 >= 0) row_token[slot1] = tok;
    slots[tok] = make_int2(slot0, slot1);
}

// Fused expert MLP v6 (verified 76us) + fp8 Y out: 256 threads (4 waves),
// 64 rows/block, e = bid&7. 16 tokens/wave -> 3 waves/SIMD. Zero-shuffle
// H->B via permuted W2 pack. W1 2-buf + W2 3-buf LDS, 1-ahead prefetch,
// counted vmcnt(2), 1 barrier/step.
__global__ __launch_bounds__(256, 3) void k_mlp(const unsigned char* __restrict__ xf8,
                                                const unsigned char* __restrict__ w1p,
                                                const unsigned char* __restrict__ w2p,
                                                const float* __restrict__ b1,
                                                const float* __restrict__ b2,
                                                const int* __restrict__ cnt,
                                                const int* __restrict__ row_token,
                                                unsigned char* __restrict__ Y) {
    int bid = blockIdx.x;
    int e = bid & 7;
    int row0 = (bid >> 3) * 64;
    int nrows = min(cnt[e * CNT_STRIDE], BE);
    if (row0 >= nrows) return;

    __shared__ char smem[45056];
    char* const W1S0 = smem;
    char* const W1S1 = smem + 8192;
    char* const W2S0 = smem + 16384;
    char* const W2S1 = smem + 24576;
    char* const W2S2 = smem + 32768;
    char* const b1lds = smem + 40960;

    int t = threadIdx.x;
    int w = t >> 6, lane = t & 63;
    int l15 = lane & 15, l4 = lane >> 4;

    const unsigned char* w1e = w1p + (size_t)e * 262144;
    const unsigned char* w2e = w2p + (size_t)e * 262144;

    // tokens + X -> VGPR (8 loads)
    int ri = row0 + w * 16 + l15;
    int tok0 = (ri < nrows) ? row_token[e * BE + ri] : 0;
    long xr[8];
#pragma unroll
    for (int ks = 0; ks < 8; ++ks)
        xr[ks] = *(const long*)(xf8 + (size_t)tok0 * 256 + ks * 32 + l4 * 8);

    // prologue: b1, W1(0), W2(0)
    GL16((const char*)(b1 + e * HIDN) + t * 16, b1lds + t * 16);
    GL16(w1e + t * 16, W1S0 + t * 16);
    GL16(w1e + 4096 + t * 16, W1S0 + 4096 + t * 16);
    GL16(w2e + t * 16, W2S0 + t * 16);
    GL16(w2e + 4096 + t * 16, W2S0 + 4096 + t * 16);
    __builtin_amdgcn_sched_barrier(0);
    asm volatile("s_waitcnt vmcnt(2)" ::: "memory");
    __builtin_amdgcn_s_barrier();
    __builtin_amdgcn_sched_barrier(0);

    f32x4 yacc[16];
#pragma unroll
    for (int nc = 0; nc < 16; ++nc) yacc[nc] = f32x4{0.f, 0.f, 0.f, 0.f};

    long hfA = 0, hfB = 0;

    auto STEP = [&](const char* w1c, const char* w2r, char* w1f_, char* w2f_,
                    const unsigned char* g1, const unsigned char* g2,
                    bool doStage, bool doB, long hin, long& hout,
                    int b1off, bool last) {
        if (doStage) {
            GL16(g1 + t * 16, w1f_ + t * 16);
            GL16(g1 + 4096 + t * 16, w1f_ + 4096 + t * 16);
            GL16(g2 + t * 16, w2f_ + t * 16);
            GL16(g2 + 4096 + t * 16, w2f_ + 4096 + t * 16);
        }
        // A: ha[h] = W1-tile(h) @ X   (D: col=token l15, row=hid l4*4+j)
        long w1fr[2][8];
#pragma unroll
        for (int h = 0; h < 2; ++h)
#pragma unroll
            for (int kp = 0; kp < 4; ++kp) {
                long2v q = *(const long2v*)(w1c + (h * 4 + kp) * 1024 + lane * 16);
                w1fr[h][kp * 2] = q.x;
                w1fr[h][kp * 2 + 1] = q.y;
            }
        f32x4 ha0 = f32x4{0.f, 0.f, 0.f, 0.f};
        f32x4 ha1 = f32x4{0.f, 0.f, 0.f, 0.f};
#pragma unroll
        for (int ks = 0; ks < 8; ++ks) {
            ha0 = mfma8(w1fr[0][ks], xr[ks], ha0);
            ha1 = mfma8(w1fr[1][ks], xr[ks], ha1);
        }
        // B: yacc += W2(prev) @ H(prev)  (A=W2, B=H; zero shuffles)
        if (doB) {
#pragma unroll
            for (int np = 0; np < 8; ++np) {
                long2v q = *(const long2v*)(w2r + np * 1024 + lane * 16);
                yacc[np * 2]     = mfma8(q.x, hin, yacc[np * 2]);
                yacc[np * 2 + 1] = mfma8(q.y, hin, yacc[np * 2 + 1]);
            }
        }
        // gelu (sigmoid form) + pack -> hout (natural order = B-operand)
        float4 bv0 = *(const float4*)(b1lds + b1off + l4 * 16);
        float4 bv1 = *(const float4*)(b1lds + b1off + 64 + l4 * 16);
        float g[4];
#pragma unroll
        for (int j = 0; j < 4; ++j) {
            float vv = ha0[j] + ((const float*)&bv0)[j];
            g[j] = vv * __builtin_amdgcn_rcpf(1.0f + __builtin_amdgcn_exp2f(-2.4554672f * vv));
        }
        unsigned p0 = pk8_hi(g[2], g[3], pk8_lo(g[0], g[1], 0u));
#pragma unroll
        for (int j = 0; j < 4; ++j) {
            float vv = ha1[j] + ((const float*)&bv1)[j];
            g[j] = vv * __builtin_amdgcn_rcpf(1.0f + __builtin_amdgcn_exp2f(-2.4554672f * vv));
        }
        unsigned p1 = pk8_hi(g[2], g[3], pk8_lo(g[0], g[1], 0u));
        hout = (long)(((unsigned long)p1 << 32) | (unsigned long)p0);

        __builtin_amdgcn_sched_barrier(0);
        if (last) asm volatile("s_waitcnt vmcnt(0)" ::: "memory");
        else      asm volatile("s_waitcnt vmcnt(2)" ::: "memory");
        __builtin_amdgcn_s_barrier();
        __builtin_amdgcn_sched_barrier(0);
    };

    const char *w1r = W1S0, *w1f = W1S1;
    const char *w2red = W2S2, *w2cur = W2S0, *w2fil = W2S1;
    const unsigned char* g1 = w1e + 8192;
    const unsigned char* g2 = w2e + 8192;
    int b1off = 0;

#define ROTATE() { const char* _a = w1r; w1r = w1f; w1f = _a; \
                   const char* _b = w2red; w2red = w2cur; w2cur = w2fil; w2fil = _b; \
                   g1 += 8192; g2 += 8192; b1off += 128; }

    // step 0: A only, produce h(0)->hfA
    STEP(w1r, w2red, (char*)w1f, (char*)w2fil, g1, g2, true, false, hfB, hfA, b1off, false);
    ROTATE();
    for (int i = 0; i < 5; ++i) {
        STEP(w1r, w2red, (char*)w1f, (char*)w2fil, g1, g2, true, true, hfA, hfB, b1off, false); ROTATE();
        STEP(w1r, w2red, (char*)w1f, (char*)w2fil, g1, g2, true, true, hfB, hfA, b1off, false); ROTATE();
        STEP(w1r, w2red, (char*)w1f, (char*)w2fil, g1, g2, true, true, hfA, hfB, b1off, false); ROTATE();
        STEP(w1r, w2red, (char*)w1f, (char*)w2fil, g1, g2, true, true, hfB, hfA, b1off, false); ROTATE();
        STEP(w1r, w2red, (char*)w1f, (char*)w2fil, g1, g2, true, true, hfA, hfB, b1off, false); ROTATE();
        STEP(w1r, w2red, (char*)w1f, (char*)w2fil, g1, g2, true, true, hfB, hfA, b1off, false); ROTATE();
    }
    // step 31: no stage, consume h(30)=hfA, produce h(31)=hfB
    STEP(w1r, w2red, (char*)w1f, (char*)w2fil, g1, g2, false, true, hfA, hfB, b1off, true);
    // final B: h(31) @ W2(31) (= w2cur)
#pragma unroll
    for (int np = 0; np < 8; ++np) {
        long2v q = *(const long2v*)(w2cur + np * 1024 + lane * 16);
        yacc[np * 2]     = mfma8(q.x, hfB, yacc[np * 2]);
        yacc[np * 2 + 1] = mfma8(q.y, hfB, yacc[np * 2 + 1]);
    }
#undef ROTATE

    // epilogue: +b2, pack fp8 (4 outs/word), 264B-pitch LDS transpose,
    // coalesced 256B-row copy out.
    // yacc layout: col l15 = token (w*16+l15), rows l4*4+j = outs of nc.
    __syncthreads();
    int lrow = w * 16 + l15;
#pragma unroll
    for (int nc = 0; nc < 16; ++nc) {
        float4 bv = *(const float4*)(b2 + e * 256 + nc * 16 + l4 * 4);
        float a0 = yacc[nc][0] + bv.x, a1 = yacc[nc][1] + bv.y;
        float a2 = yacc[nc][2] + bv.z, a3 = yacc[nc][3] + bv.w;
        unsigned pkv = pk8_hi(a2, a3, pk8_lo(a0, a1, 0u));
        *(unsigned*)(smem + lrow * 264 + nc * 16 + l4 * 4) = pkv;
    }
    __syncthreads();
    {
        char* Yg = (char*)(Y + ((size_t)e * BE + row0) * 256);
#pragma unroll
        for (int i = 0; i < 4; ++i) {
            int flat = i * 4096 + t * 16;
            int row = flat >> 8, off = flat & 255;
            *(int4*)(Yg + flat) = *(const int4*)(smem + row * 264 + off);
        }
    }
}

// Gather expert outputs (fp8), gate, add residual, write NCHW.
__global__ __launch_bounds__(256) void k_gather(const float* __restrict__ input,
                                                const unsigned char* __restrict__ Y,
                                                const int2* __restrict__ slots,
                                                const float2* __restrict__ gates,
                                                const float* __restrict__ ls,
                                                float* __restrict__ out) {
    __shared__ float acc[32][257];
    int t = threadIdx.x;
    int n = blockIdx.x >> 5, y = blockIdx.x & 31;

    {
        int tl = t & 31, chunk = t >> 5;
        int tok = n * 1024 + y * 32 + tl;
        int2  sl = slots[tok];
        float2 gw = gates[tok];
        int c0 = chunk * 32;
#pragma unroll
        for (int i = 0; i < 4; ++i) {
            int c = c0 + i * 8;
            float v[8];
#pragma unroll
            for (int k = 0; k < 8; ++k) v[k] = 0.f;
            if (sl.x >= 0) {
                uint2 wv = *(const uint2*)(Y + (size_t)sl.x * 256 + c);
                float d0[4], d1[4];
                dec8x4(wv.x, d0);
                dec8x4(wv.y, d1);
#pragma unroll
                for (int k = 0; k < 4; ++k) {
                    v[k]     += gw.x * d0[k];
                    v[k + 4] += gw.x * d1[k];
                }
            }
            if (sl.y >= 0) {
                uint2 wv = *(const uint2*)(Y + (size_t)sl.y * 256 + c);
                float d0[4], d1[4];
                dec8x4(wv.x, d0);
                dec8x4(wv.y, d1);
#pragma unroll
                for (int k = 0; k < 4; ++k) {
                    v[k]     += gw.y * d0[k];
                    v[k + 4] += gw.y * d1[k];
                }
            }
#pragma unroll
            for (int k = 0; k < 8; ++k) acc[tl][c + k] = v[k];
        }
    }
    __syncthreads();
    {
        int x = t & 31, c8 = t >> 5;
        size_t base = (size_t)n * 256 * 1024 + (size_t)y * 32 + x;
#pragma unroll
        for (int p = 0; p < 32; ++p) {
            int c = p * 8 + c8;
            size_t id = base + (size_t)c * 1024;
            out[id] = input[id] + ls[c] * acc[x][c];
        }
    }
}

extern "C" void kernel_launch(void* const* d_in, const int* in_sizes, int n_in,
                              void* d_out, int out_size, void* d_ws, size_t ws_size,
                              hipStream_t stream) {
    const float* input = (const float*)d_in[0];
    const float* dwk   = (const float*)d_in[1];
    const float* dwb   = (const float*)d_in[2];
    const float* gamma = (const float*)d_in[3];
    const float* beta  = (const float*)d_in[4];
    const float* rw    = (const float*)d_in[5];
    const float* w1    = (const float*)d_in[6];
    const float* b1    = (const float*)d_in[7];
    const float* w2    = (const float*)d_in[8];
    const float* b2    = (const float*)d_in[9];
    const float* ls    = (const float*)d_in[10];

    char* ws = (char*)d_ws;
    // xc8 (16.8MB fp8 conv out) aliases Yb (21MB fp8): xc8 dead before k_mlp writes Yb.
    unsigned char*  xc8  = (unsigned char*)ws;
    unsigned char*  Yb   = (unsigned char*)ws;
    unsigned*       xf8  = (unsigned*)(ws + 83886080);         // 8MB fp8 x
    unsigned char*  w1p  = (unsigned char*)(ws + 100663296);   // 2MB paired tiles
    unsigned char*  w2p  = (unsigned char*)(ws + 104857600);   // 2MB permuted tiles
    int*            rtok = (int*)(ws + 109051904);             // 320KB
    int2*           slots = (int2*)(ws + 109379584);           // 256KB
    float2*         gates = (float2*)(ws + 109641728);         // 256KB
    int*            e01  = (int*)(ws + 109903872);             // 128KB
    int*            cnt  = (int*)(ws + 110035968);             // 8*64 ints

    k_conv<<<9216, 256, 0, stream>>>(input, dwk, dwb, w1, w2, xc8, w1p, w2p, cnt);
    k_lnr<<<1024, 512, 0, stream>>>(xc8, gamma, beta, rw, xf8, e01, gates);
    k_assign<<<128, 256, 0, stream>>>(e01, cnt, rtok, slots);
    k_mlp<<<1280, 256, 0, stream>>>((const unsigned char*)xf8, w1p, w2p, b1, b2, cnt, rtok, Yb);
    k_gather<<<1024, 256, 0, stream>>>(input, Yb, slots, gates, ls, (float*)d_out);
}